// Round 3
// baseline (323.413 us; speedup 1.0000x reference)
//
#include <hip/hip_runtime.h>
#include <stdint.h>

#define NANCH 138240      // 15 * 96 * 96
#define B_CNT 32
#define PRE 1024
#define POST 256
#define BINS 8192         // 13-bit prefix histogram
#define CAP 4096          // candidate cap (expected ~1.1k)
#define SBLK 9            // blocks per batch for score/compact
#define SITER 15          // 9 * 15 * 1024 == 138240

typedef unsigned long long u64;

// ---- score: log_softmax over 2 classes, value = logp[class=1] -------------
__device__ __forceinline__ float score_at(const float* __restrict__ cb, int idx) {
    float x0 = cb[idx];
    float x1 = cb[idx + NANCH];
    float m  = fmaxf(x0, x1);
    float e0 = expf(x0 - m);
    float e1 = expf(x1 - m);
    return (x1 - m) - logf(e0 + e1);
}

// descending-score sortable key (ascending uint = descending score)
__device__ __forceinline__ unsigned key32(float sc) {
    unsigned u = __float_as_uint(sc);
    unsigned s = (u & 0x80000000u) ? ~u : (u | 0x80000000u);
    return ~s;
}

// ---- box decode (no FMA contraction; matches numpy fp32 op-for-op) --------
__device__ __forceinline__ void decode_box(const float* __restrict__ reg,
                                           const float* __restrict__ anch,
                                           int b, int idx, float box[4]) {
    const float* rb = reg + (size_t)b * 4 * NANCH;
    float dx = rb[idx];
    float dy = rb[idx + NANCH];
    float dw = rb[idx + 2 * NANCH];
    float dh = rb[idx + 3 * NANCH];
    float ax1 = anch[idx * 4 + 0], ay1 = anch[idx * 4 + 1];
    float ax2 = anch[idx * 4 + 2], ay2 = anch[idx * 4 + 3];
    float aw  = __fadd_rn(__fsub_rn(ax2, ax1), 1.0f);
    float ah  = __fadd_rn(__fsub_rn(ay2, ay1), 1.0f);
    float acx = __fadd_rn(ax1, __fmul_rn(0.5f, aw));
    float acy = __fadd_rn(ay1, __fmul_rn(0.5f, ah));
    float pcx = __fadd_rn(__fmul_rn(dx, aw), acx);
    float pcy = __fadd_rn(__fmul_rn(dy, ah), acy);
    float pw  = __fmul_rn(expf(dw), aw);
    float ph  = __fmul_rn(expf(dh), ah);
    float hx  = __fmul_rn(0.5f, pw);
    float hy  = __fmul_rn(0.5f, ph);
    box[0] = fminf(fmaxf(__fsub_rn(pcx, hx), 0.0f), 767.0f);
    box[1] = fminf(fmaxf(__fsub_rn(pcy, hy), 0.0f), 767.0f);
    box[2] = fminf(fmaxf(__fadd_rn(pcx, hx), 0.0f), 767.0f);
    box[3] = fminf(fmaxf(__fadd_rn(pcy, hy), 0.0f), 767.0f);
}

// ---- stage 1: grid-wide scoring + per-batch global histogram --------------
__global__ __launch_bounds__(1024) void score_kernel(const float* __restrict__ cls,
                                                     unsigned* __restrict__ hist) {
    __shared__ unsigned h[BINS];
    const int b = blockIdx.y;
    const int t = threadIdx.x;
    for (int i = t; i < BINS; i += 1024) h[i] = 0;
    __syncthreads();
    const float* cb = cls + (size_t)b * 2 * NANCH;
    const int base = blockIdx.x * (SITER * 1024);
    for (int k = 0; k < SITER; ++k) {
        int idx = base + k * 1024 + t;
        unsigned key = key32(score_at(cb, idx));
        atomicAdd(&h[key >> 19], 1u);
    }
    __syncthreads();
    unsigned* hb = hist + (size_t)b * BINS;
    for (int i = t; i < BINS; i += 1024) {
        unsigned c = h[i];
        if (c) atomicAdd(&hb[i], c);
    }
}

// ---- stage 2: per-batch rank-1024 crossing bin ----------------------------
__global__ __launch_bounds__(1024) void bstar_kernel(const unsigned* __restrict__ hist,
                                                     int* __restrict__ bstar) {
    __shared__ unsigned s_part[1024];
    __shared__ int s_b;
    const int b = blockIdx.x;
    const int t = threadIdx.x;
    const unsigned* hb = hist + (size_t)b * BINS;
    unsigned bin[8];
    unsigned seg = 0;
    for (int i = 0; i < 8; ++i) { bin[i] = hb[t * 8 + i]; seg += bin[i]; }
    s_part[t] = seg;
    __syncthreads();
    for (int off = 1; off < 1024; off <<= 1) {
        unsigned v = (t >= off) ? s_part[t - off] : 0u;
        __syncthreads();
        s_part[t] += v;
        __syncthreads();
    }
    unsigned incl = s_part[t];
    unsigned excl = incl - seg;
    if (incl >= PRE && excl < PRE) {
        unsigned cum = excl;
        int bs = t * 8 + 7;
        for (int i = 0; i < 8; ++i) {
            if (cum + bin[i] >= PRE) { bs = t * 8 + i; break; }
            cum += bin[i];
        }
        s_b = bs;
    }
    __syncthreads();
    if (t == 0) bstar[b] = s_b;
}

// ---- stage 3: grid-wide compaction of candidates --------------------------
__global__ __launch_bounds__(1024) void compact_kernel(const float* __restrict__ cls,
                                                       const int* __restrict__ bstar,
                                                       int* __restrict__ cnt,
                                                       u64* __restrict__ cand) {
    const int b = blockIdx.y;
    const int t = threadIdx.x;
    const float* cb = cls + (size_t)b * 2 * NANCH;
    const int bs = bstar[b];
    const int base = blockIdx.x * (SITER * 1024);
    for (int k = 0; k < SITER; ++k) {
        int idx = base + k * 1024 + t;
        unsigned key = key32(score_at(cb, idx));
        if ((int)(key >> 19) <= bs) {
            int pos = atomicAdd(&cnt[b], 1);
            if (pos < CAP) cand[(size_t)b * CAP + pos] = ((u64)key << 32) | (unsigned)idx;
        }
    }
}

// ---- stage 4: per-batch bitonic sort + decode + emit top-1024 -------------
__global__ __launch_bounds__(1024) void sort_kernel(const u64* __restrict__ cand,
                                                    const int* __restrict__ cnt,
                                                    const float* __restrict__ reg,
                                                    const float* __restrict__ anch,
                                                    float* __restrict__ topS,
                                                    float* __restrict__ topB) {
    __shared__ u64 s_keys[CAP];   // 32 KB
    const int b = blockIdx.x;
    const int t = threadIdx.x;
    int n = cnt[b]; if (n > CAP) n = CAP;
    for (int i = t; i < CAP; i += 1024)
        s_keys[i] = (i < n) ? cand[(size_t)b * CAP + i] : 0xFFFFFFFFFFFFFFFFull;
    __syncthreads();

    // bitonic sort ascending (keys distinct: idx baked into low bits)
    for (int k = 2; k <= CAP; k <<= 1) {
        for (int j = k >> 1; j > 0; j >>= 1) {
            for (int i = t; i < CAP; i += 1024) {
                int ixj = i ^ j;
                if (ixj > i) {
                    bool up = ((i & k) == 0);
                    u64 a = s_keys[i], c = s_keys[ixj];
                    if ((a > c) == up) { s_keys[i] = c; s_keys[ixj] = a; }
                }
            }
            __syncthreads();
        }
    }

    if (t < PRE) {
        u64 key = s_keys[t];
        int idx = (int)(key & 0xFFFFFFFFu);
        unsigned ks = (unsigned)(key >> 32);
        unsigned s  = ~ks;
        unsigned u  = (s & 0x80000000u) ? (s & 0x7FFFFFFFu) : ~s;
        float sc = __uint_as_float(u);
        float box[4];
        decode_box(reg, anch, b, idx, box);
        topS[b * PRE + t] = sc;
        float* tb = topB + ((size_t)b * PRE + t) * 4;
        tb[0] = box[0]; tb[1] = box[1]; tb[2] = box[2]; tb[3] = box[3];
    }
}

// ---- kernel 5: suppression bitmask (iou > 0.7 for j > i) ------------------
__global__ __launch_bounds__(1024) void mask_kernel(const float* __restrict__ topB,
                                                    u64* __restrict__ masks) {
    const int w = blockIdx.x;   // 64-col chunk: 0..15
    const int b = blockIdx.y;
    const int i = threadIdx.x;  // row 0..1023
    __shared__ float sx1[64], sy1[64], sx2[64], sy2[64], sar[64];
    if (i < 64) {
        const float* p = topB + ((size_t)b * PRE + w * 64 + i) * 4;
        float x1 = p[0], y1 = p[1], x2 = p[2], y2 = p[3];
        sx1[i] = x1; sy1[i] = y1; sx2[i] = x2; sy2[i] = y2;
        sar[i] = __fmul_rn(__fadd_rn(__fsub_rn(x2, x1), 1.0f),
                           __fadd_rn(__fsub_rn(y2, y1), 1.0f));
    }
    __syncthreads();
    const float* p = topB + ((size_t)b * PRE + i) * 4;
    float x1 = p[0], y1 = p[1], x2 = p[2], y2 = p[3];
    float ar = __fmul_rn(__fadd_rn(__fsub_rn(x2, x1), 1.0f),
                         __fadd_rn(__fsub_rn(y2, y1), 1.0f));
    u64 m = 0ull;
    const int jbase = w * 64;
    for (int j = 0; j < 64; j++) {
        int jj = jbase + j;
        if (jj > i) {
            float ix1 = fmaxf(x1, sx1[j]);
            float iy1 = fmaxf(y1, sy1[j]);
            float ix2 = fminf(x2, sx2[j]);
            float iy2 = fminf(y2, sy2[j]);
            float iw = fmaxf(__fadd_rn(__fsub_rn(ix2, ix1), 1.0f), 0.0f);
            float ih = fmaxf(__fadd_rn(__fsub_rn(iy2, iy1), 1.0f), 0.0f);
            float inter = __fmul_rn(iw, ih);
            float denom = __fsub_rn(__fadd_rn(ar, sar[j]), inter);
            float iou = __fdiv_rn(inter, denom);
            if (iou > 0.7f) m |= (1ull << j);
        }
    }
    masks[((size_t)b * PRE + i) * 16 + w] = m;
}

// ---- 64-bit helpers over wave --------------------------------------------
__device__ __forceinline__ u64 shfl_xor_u64(u64 v, int lanemask) {
    int lo = __shfl_xor((int)(v & 0xFFFFFFFFull), lanemask);
    int hi = __shfl_xor((int)(v >> 32), lanemask);
    return ((u64)(unsigned)hi << 32) | (unsigned)lo;
}

// ---- kernel 6: chunked wave-parallel greedy NMS ---------------------------
__global__ __launch_bounds__(64) void nms_kernel(const u64* __restrict__ masks,
                                                 const float* __restrict__ topS,
                                                 const float* __restrict__ topB,
                                                 float* __restrict__ out) {
    const int b = blockIdx.x;
    const int t = threadIdx.x;      // 0..63
    __shared__ u64 rem[16];
    __shared__ int kept[POST];
    __shared__ int s_nk;
    if (t < 16) rem[t] = 0ull;
    __syncthreads();

    const u64* mb = masks + (size_t)b * PRE * 16;
    const int w = t >> 2, g = t & 3;   // cross-chunk role: word w, row-group g
    int prefix = 0;

    for (int c = 0; c < 16; ++c) {
        u64 dv = mb[((size_t)(c * 64 + t)) * 16 + c];
        int dlo = (int)(dv & 0xFFFFFFFFull);
        int dhi = (int)(dv >> 32);

        u64 cw[16];
        #pragma unroll
        for (int k = 0; k < 16; ++k)
            cw[k] = mb[((size_t)(c * 64 + g * 16 + k)) * 16 + w];

        u64 alive = ~rem[c];

        for (int l = 0; l < 64; ++l) {
            unsigned lo = (unsigned)__builtin_amdgcn_readlane(dlo, l);
            unsigned hi = (unsigned)__builtin_amdgcn_readlane(dhi, l);
            u64 dl = ((u64)hi << 32) | lo;
            u64 a = (alive >> l) & 1ull;
            alive &= ~(a ? dl : 0ull);
        }

        if ((alive >> t) & 1ull) {
            int pos = prefix + (int)__popcll(alive & ((1ull << t) - 1ull));
            if (pos < POST) kept[pos] = c * 64 + t;
        }
        prefix += (int)__popcll(alive);

        u64 acc = 0ull;
        #pragma unroll
        for (int k = 0; k < 16; ++k)
            if ((alive >> (g * 16 + k)) & 1ull) acc |= cw[k];
        acc |= shfl_xor_u64(acc, 1);
        acc |= shfl_xor_u64(acc, 2);
        __syncthreads();
        if (g == 0 && w > c) rem[w] |= acc;
        __syncthreads();
    }

    if (t == 0) s_nk = (prefix < POST) ? prefix : POST;
    __syncthreads();
    const int n = s_nk;

    float* ob = out + (size_t)b * POST * 5;
    for (int r = t; r < POST; r += 64) {
        if (r < n) {
            int i = kept[r];
            ob[r * 5 + 0] = topS[b * PRE + i];
            const float* tb = topB + ((size_t)b * PRE + i) * 4;
            ob[r * 5 + 1] = tb[0];
            ob[r * 5 + 2] = tb[1];
            ob[r * 5 + 3] = tb[2];
            ob[r * 5 + 4] = tb[3];
        } else {
            ob[r * 5 + 0] = 0.0f; ob[r * 5 + 1] = 0.0f; ob[r * 5 + 2] = 0.0f;
            ob[r * 5 + 3] = 0.0f; ob[r * 5 + 4] = 0.0f;
        }
    }
}

extern "C" void kernel_launch(void* const* d_in, const int* in_sizes, int n_in,
                              void* d_out, int out_size, void* d_ws, size_t ws_size,
                              hipStream_t stream) {
    const float* cls  = (const float*)d_in[0];
    const float* reg  = (const float*)d_in[1];
    const float* anch = (const float*)d_in[2];

    // workspace layout (≈7.7 MB total)
    unsigned* hist = (unsigned*)d_ws;                              // 1 MB
    int* cnt   = (int*)((char*)d_ws + (size_t)B_CNT * BINS * 4);   // 128 B
    int* bstar = cnt + B_CNT;                                      // 128 B
    u64* cand  = (u64*)((char*)d_ws + (size_t)B_CNT * BINS * 4 + 1024); // 1 MB
    float* topS = (float*)((char*)cand + (size_t)B_CNT * CAP * 8); // 128 KB
    float* topB = topS + (size_t)B_CNT * PRE;                      // 512 KB
    u64* masks = (u64*)(topB + (size_t)B_CNT * PRE * 4);           // 4 MB

    // zero hist + cnt (bstar is fully overwritten)
    hipMemsetAsync(d_ws, 0, (size_t)B_CNT * BINS * 4 + 256, stream);

    score_kernel  <<<dim3(SBLK, B_CNT), 1024, 0, stream>>>(cls, hist);
    bstar_kernel  <<<B_CNT, 1024, 0, stream>>>(hist, bstar);
    compact_kernel<<<dim3(SBLK, B_CNT), 1024, 0, stream>>>(cls, bstar, cnt, cand);
    sort_kernel   <<<B_CNT, 1024, 0, stream>>>(cand, cnt, reg, anch, topS, topB);
    mask_kernel   <<<dim3(16, B_CNT), 1024, 0, stream>>>(topB, masks);
    nms_kernel    <<<B_CNT, 64, 0, stream>>>(masks, topS, topB, (float*)d_out);
}

// Round 4
// 175.507 us; speedup vs baseline: 1.8427x; 1.8427x over previous
//
#include <hip/hip_runtime.h>
#include <stdint.h>

#define NANCH 138240      // 15 * 96 * 96
#define B_CNT 32
#define PRE 1024
#define POST 256
#define BINS 8192         // 13-bit prefix histogram
#define CAP 4096          // candidate cap (expected ~1.1k)
#define SBLK 9            // blocks per batch for score/compact
#define SITER 15          // 9 * 15 * 1024 == 138240
#define CNT_STRIDE 64     // pad per-batch counters to 256 B (atomic contention)

typedef unsigned long long u64;
typedef unsigned short u16;

// ---- score: log_softmax over 2 classes, value = logp[class=1] -------------
__device__ __forceinline__ float score_at(const float* __restrict__ cb, int idx) {
    float x0 = cb[idx];
    float x1 = cb[idx + NANCH];
    float m  = fmaxf(x0, x1);
    float e0 = expf(x0 - m);
    float e1 = expf(x1 - m);
    return (x1 - m) - logf(e0 + e1);
}

// descending-score sortable key (ascending uint = descending score)
__device__ __forceinline__ unsigned key32(float sc) {
    unsigned u = __float_as_uint(sc);
    unsigned s = (u & 0x80000000u) ? ~u : (u | 0x80000000u);
    return ~s;
}

// ---- box decode (no FMA contraction; matches numpy fp32 op-for-op) --------
__device__ __forceinline__ void decode_box(const float* __restrict__ reg,
                                           const float* __restrict__ anch,
                                           int b, int idx, float box[4]) {
    const float* rb = reg + (size_t)b * 4 * NANCH;
    float dx = rb[idx];
    float dy = rb[idx + NANCH];
    float dw = rb[idx + 2 * NANCH];
    float dh = rb[idx + 3 * NANCH];
    float ax1 = anch[idx * 4 + 0], ay1 = anch[idx * 4 + 1];
    float ax2 = anch[idx * 4 + 2], ay2 = anch[idx * 4 + 3];
    float aw  = __fadd_rn(__fsub_rn(ax2, ax1), 1.0f);
    float ah  = __fadd_rn(__fsub_rn(ay2, ay1), 1.0f);
    float acx = __fadd_rn(ax1, __fmul_rn(0.5f, aw));
    float acy = __fadd_rn(ay1, __fmul_rn(0.5f, ah));
    float pcx = __fadd_rn(__fmul_rn(dx, aw), acx);
    float pcy = __fadd_rn(__fmul_rn(dy, ah), acy);
    float pw  = __fmul_rn(expf(dw), aw);
    float ph  = __fmul_rn(expf(dh), ah);
    float hx  = __fmul_rn(0.5f, pw);
    float hy  = __fmul_rn(0.5f, ph);
    box[0] = fminf(fmaxf(__fsub_rn(pcx, hx), 0.0f), 767.0f);
    box[1] = fminf(fmaxf(__fsub_rn(pcy, hy), 0.0f), 767.0f);
    box[2] = fminf(fmaxf(__fadd_rn(pcx, hx), 0.0f), 767.0f);
    box[3] = fminf(fmaxf(__fadd_rn(pcy, hy), 0.0f), 767.0f);
}

// ---- stage 1: grid-wide scoring + per-(batch,block) u16 partial hist ------
__global__ __launch_bounds__(1024) void score_kernel(const float* __restrict__ cls,
                                                     u16* __restrict__ part) {
    __shared__ unsigned h[BINS];
    const int b = blockIdx.y;
    const int t = threadIdx.x;
    for (int i = t; i < BINS; i += 1024) h[i] = 0;
    __syncthreads();
    const float* cb = cls + (size_t)b * 2 * NANCH;
    const int base = blockIdx.x * (SITER * 1024);
    for (int k = 0; k < SITER; ++k) {
        int idx = base + k * 1024 + t;
        unsigned key = key32(score_at(cb, idx));
        atomicAdd(&h[key >> 19], 1u);
    }
    __syncthreads();
    u16* pb = part + ((size_t)(b * SBLK + blockIdx.x)) * BINS;
    for (int i = t; i < BINS; i += 1024) pb[i] = (u16)h[i];   // full overwrite
}

// ---- stage 2: per-batch rank-1024 crossing bin (sum 9 partials + scan) ----
__global__ __launch_bounds__(1024) void bstar_kernel(const u16* __restrict__ part,
                                                     int* __restrict__ bstar) {
    __shared__ unsigned s_part[1024];
    __shared__ int s_b;
    const int b = blockIdx.x;
    const int t = threadIdx.x;
    unsigned bin[8];
    #pragma unroll
    for (int i = 0; i < 8; ++i) bin[i] = 0;
    const u16* pb = part + (size_t)b * SBLK * BINS;
    for (int s = 0; s < SBLK; ++s) {
        const u16* ps = pb + (size_t)s * BINS + t * 8;
        #pragma unroll
        for (int i = 0; i < 8; ++i) bin[i] += ps[i];
    }
    unsigned seg = 0;
    #pragma unroll
    for (int i = 0; i < 8; ++i) seg += bin[i];
    s_part[t] = seg;
    __syncthreads();
    for (int off = 1; off < 1024; off <<= 1) {
        unsigned v = (t >= off) ? s_part[t - off] : 0u;
        __syncthreads();
        s_part[t] += v;
        __syncthreads();
    }
    unsigned incl = s_part[t];
    unsigned excl = incl - seg;
    if (incl >= PRE && excl < PRE) {
        unsigned cum = excl;
        int bs = t * 8 + 7;
        for (int i = 0; i < 8; ++i) {
            if (cum + bin[i] >= PRE) { bs = t * 8 + i; break; }
            cum += bin[i];
        }
        s_b = bs;
    }
    __syncthreads();
    if (t == 0) bstar[b] = s_b;
}

// ---- stage 3: compaction, block-aggregated (1 global atomic per block) ----
__global__ __launch_bounds__(1024) void compact_kernel(const float* __restrict__ cls,
                                                       const int* __restrict__ bstar,
                                                       int* __restrict__ cnt,
                                                       u64* __restrict__ cand) {
    __shared__ u64 loc[CAP];   // 32 KB
    __shared__ int lcnt;
    __shared__ int gbase;
    const int b = blockIdx.y;
    const int t = threadIdx.x;
    if (t == 0) lcnt = 0;
    __syncthreads();
    const float* cb = cls + (size_t)b * 2 * NANCH;
    const int bs = bstar[b];
    const int base = blockIdx.x * (SITER * 1024);
    for (int k = 0; k < SITER; ++k) {
        int idx = base + k * 1024 + t;
        unsigned key = key32(score_at(cb, idx));
        if ((int)(key >> 19) <= bs) {
            int pos = atomicAdd(&lcnt, 1);
            if (pos < CAP) loc[pos] = ((u64)key << 32) | (unsigned)idx;
        }
    }
    __syncthreads();
    int n = lcnt; if (n > CAP) n = CAP;
    if (t == 0) gbase = atomicAdd(&cnt[b * CNT_STRIDE], n);
    __syncthreads();
    const int gb = gbase;
    for (int i = t; i < n; i += 1024) {
        int g = gb + i;
        if (g < CAP) cand[(size_t)b * CAP + g] = loc[i];
    }
}

// ---- stage 4: per-batch bitonic sort + decode + emit top-1024 -------------
__global__ __launch_bounds__(1024) void sort_kernel(const u64* __restrict__ cand,
                                                    const int* __restrict__ cnt,
                                                    const float* __restrict__ reg,
                                                    const float* __restrict__ anch,
                                                    float* __restrict__ topS,
                                                    float* __restrict__ topB) {
    __shared__ u64 s_keys[CAP];   // 32 KB
    const int b = blockIdx.x;
    const int t = threadIdx.x;
    int n = cnt[b * CNT_STRIDE]; if (n > CAP) n = CAP;
    for (int i = t; i < CAP; i += 1024)
        s_keys[i] = (i < n) ? cand[(size_t)b * CAP + i] : 0xFFFFFFFFFFFFFFFFull;
    __syncthreads();

    // bitonic sort ascending (keys distinct: idx baked into low bits)
    for (int k = 2; k <= CAP; k <<= 1) {
        for (int j = k >> 1; j > 0; j >>= 1) {
            for (int i = t; i < CAP; i += 1024) {
                int ixj = i ^ j;
                if (ixj > i) {
                    bool up = ((i & k) == 0);
                    u64 a = s_keys[i], c = s_keys[ixj];
                    if ((a > c) == up) { s_keys[i] = c; s_keys[ixj] = a; }
                }
            }
            __syncthreads();
        }
    }

    if (t < PRE) {
        u64 key = s_keys[t];
        int idx = (int)(key & 0xFFFFFFFFu);
        unsigned ks = (unsigned)(key >> 32);
        unsigned s  = ~ks;
        unsigned u  = (s & 0x80000000u) ? (s & 0x7FFFFFFFu) : ~s;
        float sc = __uint_as_float(u);
        float box[4];
        decode_box(reg, anch, b, idx, box);
        topS[b * PRE + t] = sc;
        float* tb = topB + ((size_t)b * PRE + t) * 4;
        tb[0] = box[0]; tb[1] = box[1]; tb[2] = box[2]; tb[3] = box[3];
    }
}

// ---- stage 5: suppression bitmask (iou > 0.7 for j > i) -------------------
__global__ __launch_bounds__(1024) void mask_kernel(const float* __restrict__ topB,
                                                    u64* __restrict__ masks) {
    const int w = blockIdx.x;   // 64-col chunk: 0..15
    const int b = blockIdx.y;
    const int i = threadIdx.x;  // row 0..1023
    __shared__ float sx1[64], sy1[64], sx2[64], sy2[64], sar[64];
    if (i < 64) {
        const float* p = topB + ((size_t)b * PRE + w * 64 + i) * 4;
        float x1 = p[0], y1 = p[1], x2 = p[2], y2 = p[3];
        sx1[i] = x1; sy1[i] = y1; sx2[i] = x2; sy2[i] = y2;
        sar[i] = __fmul_rn(__fadd_rn(__fsub_rn(x2, x1), 1.0f),
                           __fadd_rn(__fsub_rn(y2, y1), 1.0f));
    }
    __syncthreads();
    const float* p = topB + ((size_t)b * PRE + i) * 4;
    float x1 = p[0], y1 = p[1], x2 = p[2], y2 = p[3];
    float ar = __fmul_rn(__fadd_rn(__fsub_rn(x2, x1), 1.0f),
                         __fadd_rn(__fsub_rn(y2, y1), 1.0f));
    u64 m = 0ull;
    const int jbase = w * 64;
    for (int j = 0; j < 64; j++) {
        int jj = jbase + j;
        if (jj > i) {
            float ix1 = fmaxf(x1, sx1[j]);
            float iy1 = fmaxf(y1, sy1[j]);
            float ix2 = fminf(x2, sx2[j]);
            float iy2 = fminf(y2, sy2[j]);
            float iw = fmaxf(__fadd_rn(__fsub_rn(ix2, ix1), 1.0f), 0.0f);
            float ih = fmaxf(__fadd_rn(__fsub_rn(iy2, iy1), 1.0f), 0.0f);
            float inter = __fmul_rn(iw, ih);
            float denom = __fsub_rn(__fadd_rn(ar, sar[j]), inter);
            float iou = __fdiv_rn(inter, denom);
            if (iou > 0.7f) m |= (1ull << j);
        }
    }
    masks[((size_t)b * PRE + i) * 16 + w] = m;
}

// ---- 64-bit helpers over wave --------------------------------------------
__device__ __forceinline__ u64 shfl_xor_u64(u64 v, int lanemask) {
    int lo = __shfl_xor((int)(v & 0xFFFFFFFFull), lanemask);
    int hi = __shfl_xor((int)(v >> 32), lanemask);
    return ((u64)(unsigned)hi << 32) | (unsigned)lo;
}

// ---- stage 6: chunked wave-parallel greedy NMS ----------------------------
__global__ __launch_bounds__(64) void nms_kernel(const u64* __restrict__ masks,
                                                 const float* __restrict__ topS,
                                                 const float* __restrict__ topB,
                                                 float* __restrict__ out) {
    const int b = blockIdx.x;
    const int t = threadIdx.x;      // 0..63
    __shared__ u64 rem[16];
    __shared__ int kept[POST];
    __shared__ int s_nk;
    if (t < 16) rem[t] = 0ull;
    __syncthreads();

    const u64* mb = masks + (size_t)b * PRE * 16;
    const int w = t >> 2, g = t & 3;   // cross-chunk role: word w, row-group g
    int prefix = 0;

    for (int c = 0; c < 16; ++c) {
        u64 dv = mb[((size_t)(c * 64 + t)) * 16 + c];
        int dlo = (int)(dv & 0xFFFFFFFFull);
        int dhi = (int)(dv >> 32);

        u64 cw[16];
        #pragma unroll
        for (int k = 0; k < 16; ++k)
            cw[k] = mb[((size_t)(c * 64 + g * 16 + k)) * 16 + w];

        u64 alive = ~rem[c];

        for (int l = 0; l < 64; ++l) {
            unsigned lo = (unsigned)__builtin_amdgcn_readlane(dlo, l);
            unsigned hi = (unsigned)__builtin_amdgcn_readlane(dhi, l);
            u64 dl = ((u64)hi << 32) | lo;
            u64 a = (alive >> l) & 1ull;
            alive &= ~(a ? dl : 0ull);
        }

        if ((alive >> t) & 1ull) {
            int pos = prefix + (int)__popcll(alive & ((1ull << t) - 1ull));
            if (pos < POST) kept[pos] = c * 64 + t;
        }
        prefix += (int)__popcll(alive);

        u64 acc = 0ull;
        #pragma unroll
        for (int k = 0; k < 16; ++k)
            if ((alive >> (g * 16 + k)) & 1ull) acc |= cw[k];
        acc |= shfl_xor_u64(acc, 1);
        acc |= shfl_xor_u64(acc, 2);
        __syncthreads();
        if (g == 0 && w > c) rem[w] |= acc;
        __syncthreads();
    }

    if (t == 0) s_nk = (prefix < POST) ? prefix : POST;
    __syncthreads();
    const int n = s_nk;

    float* ob = out + (size_t)b * POST * 5;
    for (int r = t; r < POST; r += 64) {
        if (r < n) {
            int i = kept[r];
            ob[r * 5 + 0] = topS[b * PRE + i];
            const float* tb = topB + ((size_t)b * PRE + i) * 4;
            ob[r * 5 + 1] = tb[0];
            ob[r * 5 + 2] = tb[1];
            ob[r * 5 + 3] = tb[2];
            ob[r * 5 + 4] = tb[3];
        } else {
            ob[r * 5 + 0] = 0.0f; ob[r * 5 + 1] = 0.0f; ob[r * 5 + 2] = 0.0f;
            ob[r * 5 + 3] = 0.0f; ob[r * 5 + 4] = 0.0f;
        }
    }
}

extern "C" void kernel_launch(void* const* d_in, const int* in_sizes, int n_in,
                              void* d_out, int out_size, void* d_ws, size_t ws_size,
                              hipStream_t stream) {
    const float* cls  = (const float*)d_in[0];
    const float* reg  = (const float*)d_in[1];
    const float* anch = (const float*)d_in[2];

    // workspace layout (~6.2 MB peak; part aliases the masks region):
    //   [0,       8192)    cnt   (32 counters, 256-B stride)
    //   [8192,    8448)    bstar
    //   [8448,    139520)  topS  32*1024 f32
    //   [139520,  663808)  topB  32*1024*4 f32
    //   [663808,  1712384) cand  32*4096 u64
    //   [1712384, ...)     masks 32*1024*16 u64 (stage 5+)
    //                      part  32*9*8192 u16  (stages 1-2, same offset)
    char* ws = (char*)d_ws;
    int*   cnt   = (int*)ws;
    int*   bstar = (int*)(ws + 8192);
    float* topS  = (float*)(ws + 8448);
    float* topB  = (float*)(ws + 139520);
    u64*   cand  = (u64*)(ws + 663808);
    u64*   masks = (u64*)(ws + 1712384);
    u16*   part  = (u16*)(ws + 1712384);

    hipMemsetAsync(cnt, 0, 8192, stream);

    score_kernel  <<<dim3(SBLK, B_CNT), 1024, 0, stream>>>(cls, part);
    bstar_kernel  <<<B_CNT, 1024, 0, stream>>>(part, bstar);
    compact_kernel<<<dim3(SBLK, B_CNT), 1024, 0, stream>>>(cls, bstar, cnt, cand);
    sort_kernel   <<<B_CNT, 1024, 0, stream>>>(cand, cnt, reg, anch, topS, topB);
    mask_kernel   <<<dim3(16, B_CNT), 1024, 0, stream>>>(topB, masks);
    nms_kernel    <<<B_CNT, 64, 0, stream>>>(masks, topS, topB, (float*)d_out);
}

// Round 6
// 146.425 us; speedup vs baseline: 2.2087x; 1.1986x over previous
//
#include <hip/hip_runtime.h>
#include <stdint.h>

#define NANCH 138240      // 15 * 96 * 96
#define B_CNT 32
#define PRE 1024
#define POST 256
#define BINS 8192         // 13-bit prefix histogram
#define CAP 4096          // candidate cap (expected ~1.1-1.6k)
#define SBLK 9            // blocks per batch for score/compact
#define SITER 15          // 9 * 15 * 1024 == 138240
#define CNT_STRIDE 64     // pad per-batch counters to 256 B (atomic contention)
#define PAD_KEY 0xFFFFFFFFFFFFFFFFull

typedef unsigned long long u64;
typedef unsigned short u16;

// ---- score: log_softmax over 2 classes, value = logp[class=1] -------------
__device__ __forceinline__ float score_at(const float* __restrict__ cb, int idx) {
    float x0 = cb[idx];
    float x1 = cb[idx + NANCH];
    float m  = fmaxf(x0, x1);
    float e0 = expf(x0 - m);
    float e1 = expf(x1 - m);
    return (x1 - m) - logf(e0 + e1);
}

// descending-score sortable key (ascending uint = descending score)
__device__ __forceinline__ unsigned key32(float sc) {
    unsigned u = __float_as_uint(sc);
    unsigned s = (u & 0x80000000u) ? ~u : (u | 0x80000000u);
    return ~s;
}

// ---- box decode (no FMA contraction; matches numpy fp32 op-for-op) --------
__device__ __forceinline__ void decode_box(const float* __restrict__ reg,
                                           const float* __restrict__ anch,
                                           int b, int idx, float box[4]) {
    const float* rb = reg + (size_t)b * 4 * NANCH;
    float dx = rb[idx];
    float dy = rb[idx + NANCH];
    float dw = rb[idx + 2 * NANCH];
    float dh = rb[idx + 3 * NANCH];
    float ax1 = anch[idx * 4 + 0], ay1 = anch[idx * 4 + 1];
    float ax2 = anch[idx * 4 + 2], ay2 = anch[idx * 4 + 3];
    float aw  = __fadd_rn(__fsub_rn(ax2, ax1), 1.0f);
    float ah  = __fadd_rn(__fsub_rn(ay2, ay1), 1.0f);
    float acx = __fadd_rn(ax1, __fmul_rn(0.5f, aw));
    float acy = __fadd_rn(ay1, __fmul_rn(0.5f, ah));
    float pcx = __fadd_rn(__fmul_rn(dx, aw), acx);
    float pcy = __fadd_rn(__fmul_rn(dy, ah), acy);
    float pw  = __fmul_rn(expf(dw), aw);
    float ph  = __fmul_rn(expf(dh), ah);
    float hx  = __fmul_rn(0.5f, pw);
    float hy  = __fmul_rn(0.5f, ph);
    box[0] = fminf(fmaxf(__fsub_rn(pcx, hx), 0.0f), 767.0f);
    box[1] = fminf(fmaxf(__fsub_rn(pcy, hy), 0.0f), 767.0f);
    box[2] = fminf(fmaxf(__fadd_rn(pcx, hx), 0.0f), 767.0f);
    box[3] = fminf(fmaxf(__fadd_rn(pcy, hy), 0.0f), 767.0f);
}

// ---- stage 1: grid-wide scoring + per-(batch,block) u16 partial hist ------
__global__ __launch_bounds__(1024) void score_kernel(const float* __restrict__ cls,
                                                     u16* __restrict__ part) {
    __shared__ unsigned h[BINS];
    const int b = blockIdx.y;
    const int t = threadIdx.x;
    for (int i = t; i < BINS; i += 1024) h[i] = 0;
    __syncthreads();
    const float* cb = cls + (size_t)b * 2 * NANCH;
    const int base = blockIdx.x * (SITER * 1024);
    for (int k = 0; k < SITER; ++k) {
        int idx = base + k * 1024 + t;
        unsigned key = key32(score_at(cb, idx));
        atomicAdd(&h[key >> 19], 1u);
    }
    __syncthreads();
    u16* pb = part + ((size_t)(b * SBLK + blockIdx.x)) * BINS;
    for (int i = t; i < BINS; i += 1024) pb[i] = (u16)h[i];   // full overwrite
}

// ---- stage 2: per-batch rank-1024 crossing bin (sum 9 partials + scan) ----
__global__ __launch_bounds__(1024) void bstar_kernel(const u16* __restrict__ part,
                                                     int* __restrict__ bstar) {
    __shared__ unsigned s_part[1024];
    __shared__ int s_b;
    const int b = blockIdx.x;
    const int t = threadIdx.x;
    unsigned bin[8];
    #pragma unroll
    for (int i = 0; i < 8; ++i) bin[i] = 0;
    const u16* pb = part + (size_t)b * SBLK * BINS;
    for (int s = 0; s < SBLK; ++s) {
        const u16* ps = pb + (size_t)s * BINS + t * 8;
        #pragma unroll
        for (int i = 0; i < 8; ++i) bin[i] += ps[i];
    }
    unsigned seg = 0;
    #pragma unroll
    for (int i = 0; i < 8; ++i) seg += bin[i];
    s_part[t] = seg;
    __syncthreads();
    for (int off = 1; off < 1024; off <<= 1) {
        unsigned v = (t >= off) ? s_part[t - off] : 0u;
        __syncthreads();
        s_part[t] += v;
        __syncthreads();
    }
    unsigned incl = s_part[t];
    unsigned excl = incl - seg;
    if (incl >= PRE && excl < PRE) {
        unsigned cum = excl;
        int bs = t * 8 + 7;
        for (int i = 0; i < 8; ++i) {
            if (cum + bin[i] >= PRE) { bs = t * 8 + i; break; }
            cum += bin[i];
        }
        s_b = bs;
    }
    __syncthreads();
    if (t == 0) bstar[b] = s_b;
}

// ---- stage 3: compaction, block-aggregated (1 global atomic per block) ----
__global__ __launch_bounds__(1024) void compact_kernel(const float* __restrict__ cls,
                                                       const int* __restrict__ bstar,
                                                       int* __restrict__ cnt,
                                                       u64* __restrict__ cand) {
    __shared__ u64 loc[CAP];   // 32 KB
    __shared__ int lcnt;
    __shared__ int gbase;
    const int b = blockIdx.y;
    const int t = threadIdx.x;
    if (t == 0) lcnt = 0;
    __syncthreads();
    const float* cb = cls + (size_t)b * 2 * NANCH;
    const int bs = bstar[b];
    const int base = blockIdx.x * (SITER * 1024);
    for (int k = 0; k < SITER; ++k) {
        int idx = base + k * 1024 + t;
        unsigned key = key32(score_at(cb, idx));
        if ((int)(key >> 19) <= bs) {
            int pos = atomicAdd(&lcnt, 1);
            if (pos < CAP) loc[pos] = ((u64)key << 32) | (unsigned)idx;
        }
    }
    __syncthreads();
    int n = lcnt; if (n > CAP) n = CAP;
    if (t == 0) gbase = atomicAdd(&cnt[b * CNT_STRIDE], n);
    __syncthreads();
    const int gb = gbase;
    for (int i = t; i < n; i += 1024) {
        int g = gb + i;
        if (g < CAP) cand[(size_t)b * CAP + g] = loc[i];
    }
}

// ---- stage 4a: sort four 1024-runs per batch (bitonic in LDS) -------------
__global__ __launch_bounds__(512) void lsort_kernel(const int* __restrict__ cnt,
                                                    u64* __restrict__ cand) {
    __shared__ u64 s[1024];   // 8 KB
    const int c = blockIdx.x;   // chunk 0..3
    const int b = blockIdx.y;
    const int t = threadIdx.x;  // 0..511
    int n = cnt[b * CNT_STRIDE]; if (n > CAP) n = CAP;
    u64* seg = cand + (size_t)b * CAP + c * 1024;
    const int base = c * 1024;
    for (int i = t; i < 1024; i += 512)
        s[i] = (base + i < n) ? seg[i] : PAD_KEY;
    __syncthreads();
    // bitonic sort ascending over 1024 elems, 1 compare/thread/phase
    for (int k = 2; k <= 1024; k <<= 1) {
        for (int j = k >> 1; j > 0; j >>= 1) {
            int i  = ((t & ~(j - 1)) << 1) | (t & (j - 1));
            int p  = i | j;
            bool up = ((i & k) == 0);
            u64 a = s[i], bb = s[p];
            if ((a > bb) == up) { s[i] = bb; s[p] = a; }
            __syncthreads();
        }
    }
    for (int i = t; i < 1024; i += 512) seg[i] = s[i];   // write back (pads too)
}

// ---- stage 4b: 4-way rank-merge -> top-1024 + decode + emit ---------------
__global__ __launch_bounds__(1024) void merge_kernel(const u64* __restrict__ cand,
                                                     const float* __restrict__ reg,
                                                     const float* __restrict__ anch,
                                                     float* __restrict__ topS,
                                                     float* __restrict__ topB) {
    __shared__ u64 runs[CAP];    // 32 KB, 4 sorted runs of 1024
    __shared__ u64 outk[PRE];    // 8 KB
    const int b = blockIdx.x;
    const int t = threadIdx.x;   // 0..1023
    for (int i = t; i < CAP; i += 1024) runs[i] = cand[(size_t)b * CAP + i];
    __syncthreads();

    // rank(x) = own-run position + sum of lower_bounds in other runs.
    // Real keys are globally distinct (idx in low bits) -> ranks < n form a
    // permutation; pads (0xFF..) rank >= n >= 1024 so never land in outk.
    #pragma unroll
    for (int r = 0; r < 4; ++r) {
        u64 x = runs[r * 1024 + t];
        int rank = t;
        #pragma unroll
        for (int q = 0; q < 4; ++q) {
            if (q == r) continue;
            const u64* run = &runs[q * 1024];
            int lo = 0, hi = 1024;
            while (lo < hi) {               // full lower_bound (11 steps)
                int mid = (lo + hi) >> 1;
                if (run[mid] < x) lo = mid + 1; else hi = mid;
            }
            rank += lo;
        }
        if (rank < PRE) outk[rank] = x;
    }
    __syncthreads();

    // decode + emit (t spans exactly PRE)
    u64 key = outk[t];
    int idx = (int)(key & 0xFFFFFFFFu);
    unsigned ks = (unsigned)(key >> 32);
    unsigned s  = ~ks;
    unsigned u  = (s & 0x80000000u) ? (s & 0x7FFFFFFFu) : ~s;
    float sc = __uint_as_float(u);
    float box[4];
    decode_box(reg, anch, b, idx, box);
    topS[b * PRE + t] = sc;
    float* tb = topB + ((size_t)b * PRE + t) * 4;
    tb[0] = box[0]; tb[1] = box[1]; tb[2] = box[2]; tb[3] = box[3];
}

// ---- stage 5: suppression bitmask (iou > 0.7 for j > i) -------------------
__global__ __launch_bounds__(1024) void mask_kernel(const float* __restrict__ topB,
                                                    u64* __restrict__ masks) {
    const int w = blockIdx.x;   // 64-col chunk: 0..15
    const int b = blockIdx.y;
    const int i = threadIdx.x;  // row 0..1023
    __shared__ float sx1[64], sy1[64], sx2[64], sy2[64], sar[64];
    if (i < 64) {
        const float* p = topB + ((size_t)b * PRE + w * 64 + i) * 4;
        float x1 = p[0], y1 = p[1], x2 = p[2], y2 = p[3];
        sx1[i] = x1; sy1[i] = y1; sx2[i] = x2; sy2[i] = y2;
        sar[i] = __fmul_rn(__fadd_rn(__fsub_rn(x2, x1), 1.0f),
                           __fadd_rn(__fsub_rn(y2, y1), 1.0f));
    }
    __syncthreads();
    const float* p = topB + ((size_t)b * PRE + i) * 4;
    float x1 = p[0], y1 = p[1], x2 = p[2], y2 = p[3];
    float ar = __fmul_rn(__fadd_rn(__fsub_rn(x2, x1), 1.0f),
                         __fadd_rn(__fsub_rn(y2, y1), 1.0f));
    u64 m = 0ull;
    const int jbase = w * 64;
    for (int j = 0; j < 64; j++) {
        int jj = jbase + j;
        if (jj > i) {
            float ix1 = fmaxf(x1, sx1[j]);
            float iy1 = fmaxf(y1, sy1[j]);
            float ix2 = fminf(x2, sx2[j]);
            float iy2 = fminf(y2, sy2[j]);
            float iw = fmaxf(__fadd_rn(__fsub_rn(ix2, ix1), 1.0f), 0.0f);
            float ih = fmaxf(__fadd_rn(__fsub_rn(iy2, iy1), 1.0f), 0.0f);
            float inter = __fmul_rn(iw, ih);
            float denom = __fsub_rn(__fadd_rn(ar, sar[j]), inter);
            float iou = __fdiv_rn(inter, denom);
            if (iou > 0.7f) m |= (1ull << j);
        }
    }
    masks[((size_t)b * PRE + i) * 16 + w] = m;
}

// ---- 64-bit helpers over wave --------------------------------------------
__device__ __forceinline__ u64 shfl_xor_u64(u64 v, int lanemask) {
    int lo = __shfl_xor((int)(v & 0xFFFFFFFFull), lanemask);
    int hi = __shfl_xor((int)(v >> 32), lanemask);
    return ((u64)(unsigned)hi << 32) | (unsigned)lo;
}

// ---- stage 6: chunked wave-parallel greedy NMS ----------------------------
__global__ __launch_bounds__(64) void nms_kernel(const u64* __restrict__ masks,
                                                 const float* __restrict__ topS,
                                                 const float* __restrict__ topB,
                                                 float* __restrict__ out) {
    const int b = blockIdx.x;
    const int t = threadIdx.x;      // 0..63
    __shared__ u64 rem[16];
    __shared__ int kept[POST];
    __shared__ int s_nk;
    if (t < 16) rem[t] = 0ull;
    __syncthreads();

    const u64* mb = masks + (size_t)b * PRE * 16;
    const int w = t >> 2, g = t & 3;   // cross-chunk role: word w, row-group g
    int prefix = 0;

    for (int c = 0; c < 16; ++c) {
        u64 dv = mb[((size_t)(c * 64 + t)) * 16 + c];
        int dlo = (int)(dv & 0xFFFFFFFFull);
        int dhi = (int)(dv >> 32);

        u64 cw[16];
        #pragma unroll
        for (int k = 0; k < 16; ++k)
            cw[k] = mb[((size_t)(c * 64 + g * 16 + k)) * 16 + w];

        u64 alive = ~rem[c];

        for (int l = 0; l < 64; ++l) {
            unsigned lo = (unsigned)__builtin_amdgcn_readlane(dlo, l);
            unsigned hi = (unsigned)__builtin_amdgcn_readlane(dhi, l);
            u64 dl = ((u64)hi << 32) | lo;
            u64 a = (alive >> l) & 1ull;
            alive &= ~(a ? dl : 0ull);
        }

        if ((alive >> t) & 1ull) {
            int pos = prefix + (int)__popcll(alive & ((1ull << t) - 1ull));
            if (pos < POST) kept[pos] = c * 64 + t;
        }
        prefix += (int)__popcll(alive);

        u64 acc = 0ull;
        #pragma unroll
        for (int k = 0; k < 16; ++k)
            if ((alive >> (g * 16 + k)) & 1ull) acc |= cw[k];
        acc |= shfl_xor_u64(acc, 1);
        acc |= shfl_xor_u64(acc, 2);
        __syncthreads();
        if (g == 0 && w > c) rem[w] |= acc;
        __syncthreads();
    }

    if (t == 0) s_nk = (prefix < POST) ? prefix : POST;
    __syncthreads();
    const int n = s_nk;

    float* ob = out + (size_t)b * POST * 5;
    for (int r = t; r < POST; r += 64) {
        if (r < n) {
            int i = kept[r];
            ob[r * 5 + 0] = topS[b * PRE + i];
            const float* tb = topB + ((size_t)b * PRE + i) * 4;
            ob[r * 5 + 1] = tb[0];
            ob[r * 5 + 2] = tb[1];
            ob[r * 5 + 3] = tb[2];
            ob[r * 5 + 4] = tb[3];
        } else {
            ob[r * 5 + 0] = 0.0f; ob[r * 5 + 1] = 0.0f; ob[r * 5 + 2] = 0.0f;
            ob[r * 5 + 3] = 0.0f; ob[r * 5 + 4] = 0.0f;
        }
    }
}

extern "C" void kernel_launch(void* const* d_in, const int* in_sizes, int n_in,
                              void* d_out, int out_size, void* d_ws, size_t ws_size,
                              hipStream_t stream) {
    const float* cls  = (const float*)d_in[0];
    const float* reg  = (const float*)d_in[1];
    const float* anch = (const float*)d_in[2];

    // workspace layout (~6.4 MB peak; part aliases the masks region):
    //   [0,       8192)    cnt   (32 counters, 256-B stride)
    //   [8192,    8448)    bstar
    //   [8448,    139520)  topS  32*1024 f32
    //   [139520,  663808)  topB  32*1024*4 f32
    //   [663808,  1712384) cand  32*4096 u64
    //   [1712384, ...)     masks 32*1024*16 u64 (stage 5+)
    //                      part  32*9*8192 u16  (stages 1-2, same offset)
    char* ws = (char*)d_ws;
    int*   cnt   = (int*)ws;
    int*   bstar = (int*)(ws + 8192);
    float* topS  = (float*)(ws + 8448);
    float* topB  = (float*)(ws + 139520);
    u64*   cand  = (u64*)(ws + 663808);
    u64*   masks = (u64*)(ws + 1712384);
    u16*   part  = (u16*)(ws + 1712384);

    hipMemsetAsync(cnt, 0, 8192, stream);

    score_kernel  <<<dim3(SBLK, B_CNT), 1024, 0, stream>>>(cls, part);
    bstar_kernel  <<<B_CNT, 1024, 0, stream>>>(part, bstar);
    compact_kernel<<<dim3(SBLK, B_CNT), 1024, 0, stream>>>(cls, bstar, cnt, cand);
    lsort_kernel  <<<dim3(4, B_CNT), 512, 0, stream>>>(cnt, cand);
    merge_kernel  <<<B_CNT, 1024, 0, stream>>>(cand, reg, anch, topS, topB);
    mask_kernel   <<<dim3(16, B_CNT), 1024, 0, stream>>>(topB, masks);
    nms_kernel    <<<B_CNT, 64, 0, stream>>>(masks, topS, topB, (float*)d_out);
}

// Round 7
// 115.188 us; speedup vs baseline: 2.8077x; 1.2712x over previous
//
#include <hip/hip_runtime.h>
#include <stdint.h>

#define NANCH 138240      // 15 * 96 * 96
#define NANCH4 34560      // NANCH / 4
#define B_CNT 32
#define PRE 1024
#define POST 256
#define BINS 8192         // 13-bit prefix histogram
#define CAP 4096          // candidate cap (expected ~1.1-1.6k)
#define SBLK 9            // blocks per batch for score/compact
#define V4PB 3840         // float4 groups per block (9 * 3840 * 4 == 138240)
#define CNT_STRIDE 64     // pad per-batch counters to 256 B (atomic contention)
#define PAD_KEY 0xFFFFFFFFFFFFFFFFull

typedef unsigned long long u64;
typedef unsigned short u16;

// descending-score sortable key (ascending uint = descending score)
__device__ __forceinline__ unsigned key32(float sc) {
    unsigned u = __float_as_uint(sc);
    unsigned s = (u & 0x80000000u) ? ~u : (u | 0x80000000u);
    return ~s;
}

// log_softmax[1] key — float ops identical to the original score_at
__device__ __forceinline__ unsigned key_of(float x0, float x1) {
    float m  = fmaxf(x0, x1);
    float e0 = expf(x0 - m);
    float e1 = expf(x1 - m);
    float sc = (x1 - m) - logf(e0 + e1);
    return key32(sc);
}

// ---- box decode (no FMA contraction; matches numpy fp32 op-for-op) --------
__device__ __forceinline__ void decode_box(const float* __restrict__ reg,
                                           const float* __restrict__ anch,
                                           int b, int idx, float box[4]) {
    const float* rb = reg + (size_t)b * 4 * NANCH;
    float dx = rb[idx];
    float dy = rb[idx + NANCH];
    float dw = rb[idx + 2 * NANCH];
    float dh = rb[idx + 3 * NANCH];
    float ax1 = anch[idx * 4 + 0], ay1 = anch[idx * 4 + 1];
    float ax2 = anch[idx * 4 + 2], ay2 = anch[idx * 4 + 3];
    float aw  = __fadd_rn(__fsub_rn(ax2, ax1), 1.0f);
    float ah  = __fadd_rn(__fsub_rn(ay2, ay1), 1.0f);
    float acx = __fadd_rn(ax1, __fmul_rn(0.5f, aw));
    float acy = __fadd_rn(ay1, __fmul_rn(0.5f, ah));
    float pcx = __fadd_rn(__fmul_rn(dx, aw), acx);
    float pcy = __fadd_rn(__fmul_rn(dy, ah), acy);
    float pw  = __fmul_rn(expf(dw), aw);
    float ph  = __fmul_rn(expf(dh), ah);
    float hx  = __fmul_rn(0.5f, pw);
    float hy  = __fmul_rn(0.5f, ph);
    box[0] = fminf(fmaxf(__fsub_rn(pcx, hx), 0.0f), 767.0f);
    box[1] = fminf(fmaxf(__fsub_rn(pcy, hy), 0.0f), 767.0f);
    box[2] = fminf(fmaxf(__fadd_rn(pcx, hx), 0.0f), 767.0f);
    box[3] = fminf(fmaxf(__fadd_rn(pcy, hy), 0.0f), 767.0f);
}

// ---- stage 1: scoring (float4) + per-(batch,block) u16 partial hist -------
__global__ __launch_bounds__(1024) void score_kernel(const float* __restrict__ cls,
                                                     u16* __restrict__ part) {
    __shared__ unsigned h[BINS];
    const int b = blockIdx.y;
    const int t = threadIdx.x;
    for (int i = t; i < BINS; i += 1024) h[i] = 0;
    __syncthreads();
    const float4* cb4 = (const float4*)(cls + (size_t)b * 2 * NANCH);
    const int base4 = blockIdx.x * V4PB;
    for (int k = 0; k < 4; ++k) {
        int off = k * 1024 + t;
        if (off < V4PB) {
            int g4 = base4 + off;
            float4 a0 = cb4[g4];
            float4 a1 = cb4[g4 + NANCH4];
            atomicAdd(&h[key_of(a0.x, a1.x) >> 19], 1u);
            atomicAdd(&h[key_of(a0.y, a1.y) >> 19], 1u);
            atomicAdd(&h[key_of(a0.z, a1.z) >> 19], 1u);
            atomicAdd(&h[key_of(a0.w, a1.w) >> 19], 1u);
        }
    }
    __syncthreads();
    u16* pb = part + ((size_t)(b * SBLK + blockIdx.x)) * BINS;
    for (int i = t; i < BINS; i += 1024) pb[i] = (u16)h[i];   // full overwrite
}

// ---- stage 2: per-batch rank-1024 crossing bin (sum 9 partials + scan) ----
__global__ __launch_bounds__(1024) void bstar_kernel(const u16* __restrict__ part,
                                                     int* __restrict__ bstar) {
    __shared__ unsigned s_part[1024];
    __shared__ int s_b;
    const int b = blockIdx.x;
    const int t = threadIdx.x;
    unsigned bin[8];
    #pragma unroll
    for (int i = 0; i < 8; ++i) bin[i] = 0;
    const u16* pb = part + (size_t)b * SBLK * BINS;
    for (int s = 0; s < SBLK; ++s) {
        const u16* ps = pb + (size_t)s * BINS + t * 8;
        #pragma unroll
        for (int i = 0; i < 8; ++i) bin[i] += ps[i];
    }
    unsigned seg = 0;
    #pragma unroll
    for (int i = 0; i < 8; ++i) seg += bin[i];
    s_part[t] = seg;
    __syncthreads();
    for (int off = 1; off < 1024; off <<= 1) {
        unsigned v = (t >= off) ? s_part[t - off] : 0u;
        __syncthreads();
        s_part[t] += v;
        __syncthreads();
    }
    unsigned incl = s_part[t];
    unsigned excl = incl - seg;
    if (incl >= PRE && excl < PRE) {
        unsigned cum = excl;
        int bs = t * 8 + 7;
        for (int i = 0; i < 8; ++i) {
            if (cum + bin[i] >= PRE) { bs = t * 8 + i; break; }
            cum += bin[i];
        }
        s_b = bs;
    }
    __syncthreads();
    if (t == 0) bstar[b] = s_b;
}

// ---- stage 3: compaction (float4), 1 global atomic per block --------------
__global__ __launch_bounds__(1024) void compact_kernel(const float* __restrict__ cls,
                                                       const int* __restrict__ bstar,
                                                       int* __restrict__ cnt,
                                                       u64* __restrict__ cand) {
    __shared__ u64 loc[CAP];   // 32 KB
    __shared__ int lcnt;
    __shared__ int gbase;
    const int b = blockIdx.y;
    const int t = threadIdx.x;
    if (t == 0) lcnt = 0;
    __syncthreads();
    const float4* cb4 = (const float4*)(cls + (size_t)b * 2 * NANCH);
    const int bs = bstar[b];
    const int base4 = blockIdx.x * V4PB;
    for (int k = 0; k < 4; ++k) {
        int off = k * 1024 + t;
        if (off < V4PB) {
            int g4 = base4 + off;
            float4 a0 = cb4[g4];
            float4 a1 = cb4[g4 + NANCH4];
            float x0[4] = {a0.x, a0.y, a0.z, a0.w};
            float x1[4] = {a1.x, a1.y, a1.z, a1.w};
            #pragma unroll
            for (int j = 0; j < 4; ++j) {
                unsigned key = key_of(x0[j], x1[j]);
                if ((int)(key >> 19) <= bs) {
                    int pos = atomicAdd(&lcnt, 1);
                    if (pos < CAP)
                        loc[pos] = ((u64)key << 32) | (unsigned)(g4 * 4 + j);
                }
            }
        }
    }
    __syncthreads();
    int n = lcnt; if (n > CAP) n = CAP;
    if (t == 0) gbase = atomicAdd(&cnt[b * CNT_STRIDE], n);
    __syncthreads();
    const int gb = gbase;
    for (int i = t; i < n; i += 1024) {
        int g = gb + i;
        if (g < CAP) cand[(size_t)b * CAP + g] = loc[i];
    }
}

// ---- stage 4a: sort four 1024-runs per batch (bitonic in LDS) -------------
__global__ __launch_bounds__(512) void lsort_kernel(const int* __restrict__ cnt,
                                                    u64* __restrict__ cand) {
    __shared__ u64 s[1024];   // 8 KB
    const int c = blockIdx.x;   // chunk 0..3
    const int b = blockIdx.y;
    const int t = threadIdx.x;  // 0..511
    int n = cnt[b * CNT_STRIDE]; if (n > CAP) n = CAP;
    u64* seg = cand + (size_t)b * CAP + c * 1024;
    const int base = c * 1024;
    for (int i = t; i < 1024; i += 512)
        s[i] = (base + i < n) ? seg[i] : PAD_KEY;
    __syncthreads();
    for (int k = 2; k <= 1024; k <<= 1) {
        for (int j = k >> 1; j > 0; j >>= 1) {
            int i  = ((t & ~(j - 1)) << 1) | (t & (j - 1));
            int p  = i | j;
            bool up = ((i & k) == 0);
            u64 a = s[i], bb = s[p];
            if ((a > bb) == up) { s[i] = bb; s[p] = a; }
            __syncthreads();
        }
    }
    for (int i = t; i < 1024; i += 512) seg[i] = s[i];   // write back (pads too)
}

// ---- stage 4b: 4-way rank-merge -> top-1024 + decode + emit ---------------
__global__ __launch_bounds__(1024) void merge_kernel(const u64* __restrict__ cand,
                                                     const float* __restrict__ reg,
                                                     const float* __restrict__ anch,
                                                     float* __restrict__ topS,
                                                     float* __restrict__ topB) {
    __shared__ u64 runs[CAP];    // 32 KB, 4 sorted runs of 1024
    __shared__ u64 outk[PRE];    // 8 KB
    const int b = blockIdx.x;
    const int t = threadIdx.x;   // 0..1023
    for (int i = t; i < CAP; i += 1024) runs[i] = cand[(size_t)b * CAP + i];
    __syncthreads();

    #pragma unroll
    for (int r = 0; r < 4; ++r) {
        u64 x = runs[r * 1024 + t];
        int rank = t;
        #pragma unroll
        for (int q = 0; q < 4; ++q) {
            if (q == r) continue;
            const u64* run = &runs[q * 1024];
            int lo = 0, hi = 1024;
            while (lo < hi) {               // full lower_bound
                int mid = (lo + hi) >> 1;
                if (run[mid] < x) lo = mid + 1; else hi = mid;
            }
            rank += lo;
        }
        if (rank < PRE) outk[rank] = x;
    }
    __syncthreads();

    u64 key = outk[t];
    int idx = (int)(key & 0xFFFFFFFFu);
    unsigned ks = (unsigned)(key >> 32);
    unsigned s  = ~ks;
    unsigned u  = (s & 0x80000000u) ? (s & 0x7FFFFFFFu) : ~s;
    float sc = __uint_as_float(u);
    float box[4];
    decode_box(reg, anch, b, idx, box);
    topS[b * PRE + t] = sc;
    float* tb = topB + ((size_t)b * PRE + t) * 4;
    tb[0] = box[0]; tb[1] = box[1]; tb[2] = box[2]; tb[3] = box[3];
}

// ---- stage 5: suppression bitmask (iou > 0.7 for j > i; triangular) -------
__global__ __launch_bounds__(1024) void mask_kernel(const float* __restrict__ topB,
                                                    u64* __restrict__ masks) {
    const int w = blockIdx.x;   // 64-col chunk: 0..15
    const int b = blockIdx.y;
    const int i = threadIdx.x;  // row 0..1023
    __shared__ float sx1[64], sy1[64], sx2[64], sy2[64], sar[64];
    if (i < 64) {
        const float* p = topB + ((size_t)b * PRE + w * 64 + i) * 4;
        float x1 = p[0], y1 = p[1], x2 = p[2], y2 = p[3];
        sx1[i] = x1; sy1[i] = y1; sx2[i] = x2; sy2[i] = y2;
        sar[i] = __fmul_rn(__fadd_rn(__fsub_rn(x2, x1), 1.0f),
                           __fadd_rn(__fsub_rn(y2, y1), 1.0f));
    }
    __syncthreads();
    const int jbase = w * 64;
    u64* dst = &masks[((size_t)b * PRE + i) * 16 + w];
    if (i >= jbase + 63) { *dst = 0ull; return; }   // upper-triangle only
    const float* p = topB + ((size_t)b * PRE + i) * 4;
    float x1 = p[0], y1 = p[1], x2 = p[2], y2 = p[3];
    float ar = __fmul_rn(__fadd_rn(__fsub_rn(x2, x1), 1.0f),
                         __fadd_rn(__fsub_rn(y2, y1), 1.0f));
    u64 m = 0ull;
    for (int j = 0; j < 64; j++) {
        int jj = jbase + j;
        if (jj > i) {
            float ix1 = fmaxf(x1, sx1[j]);
            float iy1 = fmaxf(y1, sy1[j]);
            float ix2 = fminf(x2, sx2[j]);
            float iy2 = fminf(y2, sy2[j]);
            float iw = fmaxf(__fadd_rn(__fsub_rn(ix2, ix1), 1.0f), 0.0f);
            float ih = fmaxf(__fadd_rn(__fsub_rn(iy2, iy1), 1.0f), 0.0f);
            float inter = __fmul_rn(iw, ih);
            float denom = __fsub_rn(__fadd_rn(ar, sar[j]), inter);
            float iou = __fdiv_rn(inter, denom);
            if (iou > 0.7f) m |= (1ull << j);
        }
    }
    *dst = m;
}

// ---- 64-bit helpers over wave --------------------------------------------
__device__ __forceinline__ u64 shfl_xor_u64(u64 v, int lanemask) {
    int lo = __shfl_xor((int)(v & 0xFFFFFFFFull), lanemask);
    int hi = __shfl_xor((int)(v >> 32), lanemask);
    return ((u64)(unsigned)hi << 32) | (unsigned)lo;
}

// ---- stage 6: pipelined chunked greedy NMS with early exit ----------------
__global__ __launch_bounds__(64) void nms_kernel(const u64* __restrict__ masks,
                                                 const float* __restrict__ topS,
                                                 const float* __restrict__ topB,
                                                 float* __restrict__ out) {
    const int b = blockIdx.x;
    const int t = threadIdx.x;      // 0..63
    __shared__ u64 rem[16];
    __shared__ int kept[POST];
    __shared__ int s_nk;
    if (t < 16) rem[t] = 0ull;
    __syncthreads();

    const u64* mb = masks + (size_t)b * PRE * 16;
    const int w = t >> 2, g = t & 3;   // cross-chunk role: word w, row-group g
    int prefix = 0;

    // prefetch chunk 0
    u64 dv_cur = mb[(size_t)t * 16 + 0];
    u64 cw_cur[16];
    #pragma unroll
    for (int k = 0; k < 16; ++k)
        cw_cur[k] = mb[((size_t)(g * 16 + k)) * 16 + w];

    for (int c = 0; c < 16; ++c) {
        // issue chunk c+1 loads early; latency hides under the serial loop
        u64 dv_nxt = 0ull;
        u64 cw_nxt[16];
        if (c < 15) {
            const u64* nb = mb + (size_t)(c + 1) * 64 * 16;
            dv_nxt = nb[(size_t)t * 16 + (c + 1)];
            #pragma unroll
            for (int k = 0; k < 16; ++k)
                cw_nxt[k] = nb[((size_t)(g * 16 + k)) * 16 + w];
        } else {
            #pragma unroll
            for (int k = 0; k < 16; ++k) cw_nxt[k] = 0ull;
        }

        u64 alive = ~rem[c];
        int dlo = (int)(dv_cur & 0xFFFFFFFFull);
        int dhi = (int)(dv_cur >> 32);

        // serial greedy within chunk: register-only recurrence
        for (int l = 0; l < 64; ++l) {
            unsigned lo = (unsigned)__builtin_amdgcn_readlane(dlo, l);
            unsigned hi = (unsigned)__builtin_amdgcn_readlane(dhi, l);
            u64 dl = ((u64)hi << 32) | lo;
            u64 a = (alive >> l) & 1ull;
            alive &= ~(a ? dl : 0ull);
        }

        if ((alive >> t) & 1ull) {
            int pos = prefix + (int)__popcll(alive & ((1ull << t) - 1ull));
            if (pos < POST) kept[pos] = c * 64 + t;
        }
        prefix += (int)__popcll(alive);

        u64 acc = 0ull;
        #pragma unroll
        for (int k = 0; k < 16; ++k)
            if ((alive >> (g * 16 + k)) & 1ull) acc |= cw_cur[k];
        acc |= shfl_xor_u64(acc, 1);
        acc |= shfl_xor_u64(acc, 2);
        __syncthreads();
        if (g == 0 && w > c) rem[w] |= acc;
        __syncthreads();

        if (prefix >= POST) break;   // first POST kept found; rest irrelevant

        dv_cur = dv_nxt;
        #pragma unroll
        for (int k = 0; k < 16; ++k) cw_cur[k] = cw_nxt[k];
    }

    if (t == 0) s_nk = (prefix < POST) ? prefix : POST;
    __syncthreads();
    const int n = s_nk;

    float* ob = out + (size_t)b * POST * 5;
    for (int r = t; r < POST; r += 64) {
        if (r < n) {
            int i = kept[r];
            ob[r * 5 + 0] = topS[b * PRE + i];
            const float* tb = topB + ((size_t)b * PRE + i) * 4;
            ob[r * 5 + 1] = tb[0];
            ob[r * 5 + 2] = tb[1];
            ob[r * 5 + 3] = tb[2];
            ob[r * 5 + 4] = tb[3];
        } else {
            ob[r * 5 + 0] = 0.0f; ob[r * 5 + 1] = 0.0f; ob[r * 5 + 2] = 0.0f;
            ob[r * 5 + 3] = 0.0f; ob[r * 5 + 4] = 0.0f;
        }
    }
}

extern "C" void kernel_launch(void* const* d_in, const int* in_sizes, int n_in,
                              void* d_out, int out_size, void* d_ws, size_t ws_size,
                              hipStream_t stream) {
    const float* cls  = (const float*)d_in[0];
    const float* reg  = (const float*)d_in[1];
    const float* anch = (const float*)d_in[2];

    // workspace layout (~6.4 MB peak; part aliases the masks region):
    //   [0,       8192)    cnt   (32 counters, 256-B stride)
    //   [8192,    8448)    bstar
    //   [8448,    139520)  topS  32*1024 f32
    //   [139520,  663808)  topB  32*1024*4 f32
    //   [663808,  1712384) cand  32*4096 u64
    //   [1712384, ...)     masks 32*1024*16 u64 (stage 5+)
    //                      part  32*9*8192 u16  (stages 1-2, same offset)
    char* ws = (char*)d_ws;
    int*   cnt   = (int*)ws;
    int*   bstar = (int*)(ws + 8192);
    float* topS  = (float*)(ws + 8448);
    float* topB  = (float*)(ws + 139520);
    u64*   cand  = (u64*)(ws + 663808);
    u64*   masks = (u64*)(ws + 1712384);
    u16*   part  = (u16*)(ws + 1712384);

    hipMemsetAsync(cnt, 0, 8192, stream);

    score_kernel  <<<dim3(SBLK, B_CNT), 1024, 0, stream>>>(cls, part);
    bstar_kernel  <<<B_CNT, 1024, 0, stream>>>(part, bstar);
    compact_kernel<<<dim3(SBLK, B_CNT), 1024, 0, stream>>>(cls, bstar, cnt, cand);
    lsort_kernel  <<<dim3(4, B_CNT), 512, 0, stream>>>(cnt, cand);
    merge_kernel  <<<B_CNT, 1024, 0, stream>>>(cand, reg, anch, topS, topB);
    mask_kernel   <<<dim3(16, B_CNT), 1024, 0, stream>>>(topB, masks);
    nms_kernel    <<<B_CNT, 64, 0, stream>>>(masks, topS, topB, (float*)d_out);
}

// Round 8
// 103.032 us; speedup vs baseline: 3.1389x; 1.1180x over previous
//
#include <hip/hip_runtime.h>
#include <stdint.h>

#define NANCH 138240      // 15 * 96 * 96
#define NANCH4 34560      // NANCH / 4
#define B_CNT 32
#define PRE 1024
#define POST 256
#define BINS 8192         // 13-bit prefix histogram
#define CAP 4096          // candidate cap (expected ~1.1-1.6k)
#define SBLK 9            // blocks per batch for score/compact
#define V4PB 3840         // float4 groups per block (9 * 3840 * 4 == 138240)
#define CNT_STRIDE 64     // pad per-batch counters to 256 B (atomic contention)
#define PAD_KEY 0xFFFFFFFFFFFFFFFFull

typedef unsigned long long u64;
typedef unsigned short u16;

// descending-score sortable key (ascending uint = descending score)
__device__ __forceinline__ unsigned key32(float sc) {
    unsigned u = __float_as_uint(sc);
    unsigned s = (u & 0x80000000u) ? ~u : (u | 0x80000000u);
    return ~s;
}

// log_softmax[1] key — float ops identical to the original score_at
__device__ __forceinline__ unsigned key_of(float x0, float x1) {
    float m  = fmaxf(x0, x1);
    float e0 = expf(x0 - m);
    float e1 = expf(x1 - m);
    float sc = (x1 - m) - logf(e0 + e1);
    return key32(sc);
}

// ---- box decode (no FMA contraction; matches numpy fp32 op-for-op) --------
__device__ __forceinline__ void decode_box(const float* __restrict__ reg,
                                           const float* __restrict__ anch,
                                           int b, int idx, float box[4]) {
    const float* rb = reg + (size_t)b * 4 * NANCH;
    float dx = rb[idx];
    float dy = rb[idx + NANCH];
    float dw = rb[idx + 2 * NANCH];
    float dh = rb[idx + 3 * NANCH];
    float ax1 = anch[idx * 4 + 0], ay1 = anch[idx * 4 + 1];
    float ax2 = anch[idx * 4 + 2], ay2 = anch[idx * 4 + 3];
    float aw  = __fadd_rn(__fsub_rn(ax2, ax1), 1.0f);
    float ah  = __fadd_rn(__fsub_rn(ay2, ay1), 1.0f);
    float acx = __fadd_rn(ax1, __fmul_rn(0.5f, aw));
    float acy = __fadd_rn(ay1, __fmul_rn(0.5f, ah));
    float pcx = __fadd_rn(__fmul_rn(dx, aw), acx);
    float pcy = __fadd_rn(__fmul_rn(dy, ah), acy);
    float pw  = __fmul_rn(expf(dw), aw);
    float ph  = __fmul_rn(expf(dh), ah);
    float hx  = __fmul_rn(0.5f, pw);
    float hy  = __fmul_rn(0.5f, ph);
    box[0] = fminf(fmaxf(__fsub_rn(pcx, hx), 0.0f), 767.0f);
    box[1] = fminf(fmaxf(__fsub_rn(pcy, hy), 0.0f), 767.0f);
    box[2] = fminf(fmaxf(__fadd_rn(pcx, hx), 0.0f), 767.0f);
    box[3] = fminf(fmaxf(__fadd_rn(pcy, hy), 0.0f), 767.0f);
}

// ---- stage 1: scoring (float4) + key cache + u16 partial hist -------------
__global__ __launch_bounds__(1024) void score_kernel(const float* __restrict__ cls,
                                                     unsigned* __restrict__ keys,
                                                     u16* __restrict__ part) {
    __shared__ unsigned h[BINS];
    const int b = blockIdx.y;
    const int t = threadIdx.x;
    for (int i = t; i < BINS; i += 1024) h[i] = 0;
    __syncthreads();
    const float4* cb4 = (const float4*)(cls + (size_t)b * 2 * NANCH);
    uint4* kb4 = (uint4*)(keys + (size_t)b * NANCH);
    const int base4 = blockIdx.x * V4PB;
    for (int k = 0; k < 4; ++k) {
        int off = k * 1024 + t;
        if (off < V4PB) {
            int g4 = base4 + off;
            float4 a0 = cb4[g4];
            float4 a1 = cb4[g4 + NANCH4];
            unsigned k0 = key_of(a0.x, a1.x);
            unsigned k1 = key_of(a0.y, a1.y);
            unsigned k2 = key_of(a0.z, a1.z);
            unsigned k3 = key_of(a0.w, a1.w);
            kb4[g4] = make_uint4(k0, k1, k2, k3);
            atomicAdd(&h[k0 >> 19], 1u);
            atomicAdd(&h[k1 >> 19], 1u);
            atomicAdd(&h[k2 >> 19], 1u);
            atomicAdd(&h[k3 >> 19], 1u);
        }
    }
    __syncthreads();
    u16* pb = part + ((size_t)(b * SBLK + blockIdx.x)) * BINS;
    for (int i = t; i < BINS; i += 1024) pb[i] = (u16)h[i];   // full overwrite
}

// ---- stage 2: rank-1024 crossing bin (sum 9 partials + scan); zero cnt ----
__global__ __launch_bounds__(1024) void bstar_kernel(const u16* __restrict__ part,
                                                     int* __restrict__ bstar,
                                                     int* __restrict__ cnt) {
    __shared__ unsigned s_part[1024];
    __shared__ int s_b;
    const int b = blockIdx.x;
    const int t = threadIdx.x;
    if (t == 0) cnt[b * CNT_STRIDE] = 0;   // replaces host-side memset
    unsigned bin[8];
    #pragma unroll
    for (int i = 0; i < 8; ++i) bin[i] = 0;
    const u16* pb = part + (size_t)b * SBLK * BINS;
    for (int s = 0; s < SBLK; ++s) {
        const u16* ps = pb + (size_t)s * BINS + t * 8;
        #pragma unroll
        for (int i = 0; i < 8; ++i) bin[i] += ps[i];
    }
    unsigned seg = 0;
    #pragma unroll
    for (int i = 0; i < 8; ++i) seg += bin[i];
    s_part[t] = seg;
    __syncthreads();
    for (int off = 1; off < 1024; off <<= 1) {
        unsigned v = (t >= off) ? s_part[t - off] : 0u;
        __syncthreads();
        s_part[t] += v;
        __syncthreads();
    }
    unsigned incl = s_part[t];
    unsigned excl = incl - seg;
    if (incl >= PRE && excl < PRE) {
        unsigned cum = excl;
        int bs = t * 8 + 7;
        for (int i = 0; i < 8; ++i) {
            if (cum + bin[i] >= PRE) { bs = t * 8 + i; break; }
            cum += bin[i];
        }
        s_b = bs;
    }
    __syncthreads();
    if (t == 0) bstar[b] = s_b;
}

// ---- stage 3: compaction from cached keys (uint4 loads) -------------------
__global__ __launch_bounds__(1024) void compact_kernel(const unsigned* __restrict__ keys,
                                                       const int* __restrict__ bstar,
                                                       int* __restrict__ cnt,
                                                       u64* __restrict__ cand) {
    __shared__ u64 loc[CAP];   // 32 KB
    __shared__ int lcnt;
    __shared__ int gbase;
    const int b = blockIdx.y;
    const int t = threadIdx.x;
    if (t == 0) lcnt = 0;
    __syncthreads();
    const uint4* kb4 = (const uint4*)(keys + (size_t)b * NANCH);
    const int bs = bstar[b];
    const int base4 = blockIdx.x * V4PB;
    for (int k = 0; k < 4; ++k) {
        int off = k * 1024 + t;
        if (off < V4PB) {
            int g4 = base4 + off;
            uint4 kv = kb4[g4];
            unsigned kk[4] = {kv.x, kv.y, kv.z, kv.w};
            #pragma unroll
            for (int j = 0; j < 4; ++j) {
                if ((int)(kk[j] >> 19) <= bs) {
                    int pos = atomicAdd(&lcnt, 1);
                    if (pos < CAP)
                        loc[pos] = ((u64)kk[j] << 32) | (unsigned)(g4 * 4 + j);
                }
            }
        }
    }
    __syncthreads();
    int n = lcnt; if (n > CAP) n = CAP;
    if (t == 0) gbase = atomicAdd(&cnt[b * CNT_STRIDE], n);
    __syncthreads();
    const int gb = gbase;
    for (int i = t; i < n; i += 1024) {
        int g = gb + i;
        if (g < CAP) cand[(size_t)b * CAP + g] = loc[i];
    }
}

// ---- stage 4a: sort four 1024-runs per batch (bitonic in LDS) -------------
__global__ __launch_bounds__(512) void lsort_kernel(const int* __restrict__ cnt,
                                                    u64* __restrict__ cand) {
    __shared__ u64 s[1024];   // 8 KB
    const int c = blockIdx.x;   // chunk 0..3
    const int b = blockIdx.y;
    const int t = threadIdx.x;  // 0..511
    int n = cnt[b * CNT_STRIDE]; if (n > CAP) n = CAP;
    u64* seg = cand + (size_t)b * CAP + c * 1024;
    const int base = c * 1024;
    for (int i = t; i < 1024; i += 512)
        s[i] = (base + i < n) ? seg[i] : PAD_KEY;
    __syncthreads();
    for (int k = 2; k <= 1024; k <<= 1) {
        for (int j = k >> 1; j > 0; j >>= 1) {
            int i  = ((t & ~(j - 1)) << 1) | (t & (j - 1));
            int p  = i | j;
            bool up = ((i & k) == 0);
            u64 a = s[i], bb = s[p];
            if ((a > bb) == up) { s[i] = bb; s[p] = a; }
            __syncthreads();
        }
    }
    for (int i = t; i < 1024; i += 512) seg[i] = s[i];   // write back (pads too)
}

// ---- stage 4b: 4-way rank-merge -> top-1024 + decode + emit ---------------
__global__ __launch_bounds__(1024) void merge_kernel(const u64* __restrict__ cand,
                                                     const float* __restrict__ reg,
                                                     const float* __restrict__ anch,
                                                     float* __restrict__ topS,
                                                     float* __restrict__ topB) {
    __shared__ u64 runs[CAP];    // 32 KB, 4 sorted runs of 1024
    __shared__ u64 outk[PRE];    // 8 KB
    const int b = blockIdx.x;
    const int t = threadIdx.x;   // 0..1023
    for (int i = t; i < CAP; i += 1024) runs[i] = cand[(size_t)b * CAP + i];
    __syncthreads();

    #pragma unroll
    for (int r = 0; r < 4; ++r) {
        u64 x = runs[r * 1024 + t];
        int rank = t;
        #pragma unroll
        for (int q = 0; q < 4; ++q) {
            if (q == r) continue;
            const u64* run = &runs[q * 1024];
            int lo = 0, hi = 1024;
            while (lo < hi) {               // full lower_bound
                int mid = (lo + hi) >> 1;
                if (run[mid] < x) lo = mid + 1; else hi = mid;
            }
            rank += lo;
        }
        if (rank < PRE) outk[rank] = x;
    }
    __syncthreads();

    u64 key = outk[t];
    int idx = (int)(key & 0xFFFFFFFFu);
    unsigned ks = (unsigned)(key >> 32);
    unsigned s  = ~ks;
    unsigned u  = (s & 0x80000000u) ? (s & 0x7FFFFFFFu) : ~s;
    float sc = __uint_as_float(u);
    float box[4];
    decode_box(reg, anch, b, idx, box);
    topS[b * PRE + t] = sc;
    float* tb = topB + ((size_t)b * PRE + t) * 4;
    tb[0] = box[0]; tb[1] = box[1]; tb[2] = box[2]; tb[3] = box[3];
}

// ---- stage 5: suppression bitmask (iou > 0.7 for j > i; triangular) -------
__global__ __launch_bounds__(1024) void mask_kernel(const float* __restrict__ topB,
                                                    u64* __restrict__ masks) {
    const int w = blockIdx.x;   // 64-col chunk: 0..15
    const int b = blockIdx.y;
    const int i = threadIdx.x;  // row 0..1023
    __shared__ float sx1[64], sy1[64], sx2[64], sy2[64], sar[64];
    if (i < 64) {
        const float* p = topB + ((size_t)b * PRE + w * 64 + i) * 4;
        float x1 = p[0], y1 = p[1], x2 = p[2], y2 = p[3];
        sx1[i] = x1; sy1[i] = y1; sx2[i] = x2; sy2[i] = y2;
        sar[i] = __fmul_rn(__fadd_rn(__fsub_rn(x2, x1), 1.0f),
                           __fadd_rn(__fsub_rn(y2, y1), 1.0f));
    }
    __syncthreads();
    const int jbase = w * 64;
    u64* dst = &masks[((size_t)b * PRE + i) * 16 + w];
    if (i >= jbase + 63) { *dst = 0ull; return; }   // upper-triangle only
    const float* p = topB + ((size_t)b * PRE + i) * 4;
    float x1 = p[0], y1 = p[1], x2 = p[2], y2 = p[3];
    float ar = __fmul_rn(__fadd_rn(__fsub_rn(x2, x1), 1.0f),
                         __fadd_rn(__fsub_rn(y2, y1), 1.0f));
    u64 m = 0ull;
    for (int j = 0; j < 64; j++) {
        int jj = jbase + j;
        if (jj > i) {
            float ix1 = fmaxf(x1, sx1[j]);
            float iy1 = fmaxf(y1, sy1[j]);
            float ix2 = fminf(x2, sx2[j]);
            float iy2 = fminf(y2, sy2[j]);
            float iw = fmaxf(__fadd_rn(__fsub_rn(ix2, ix1), 1.0f), 0.0f);
            float ih = fmaxf(__fadd_rn(__fsub_rn(iy2, iy1), 1.0f), 0.0f);
            float inter = __fmul_rn(iw, ih);
            float denom = __fsub_rn(__fadd_rn(ar, sar[j]), inter);
            float iou = __fdiv_rn(inter, denom);
            if (iou > 0.7f) m |= (1ull << j);
        }
    }
    *dst = m;
}

// ---- 64-bit helpers over wave --------------------------------------------
__device__ __forceinline__ u64 shfl_xor_u64(u64 v, int lanemask) {
    int lo = __shfl_xor((int)(v & 0xFFFFFFFFull), lanemask);
    int hi = __shfl_xor((int)(v >> 32), lanemask);
    return ((u64)(unsigned)hi << 32) | (unsigned)lo;
}

// ---- stage 6: pipelined chunked greedy NMS with early exit ----------------
__global__ __launch_bounds__(64) void nms_kernel(const u64* __restrict__ masks,
                                                 const float* __restrict__ topS,
                                                 const float* __restrict__ topB,
                                                 float* __restrict__ out) {
    const int b = blockIdx.x;
    const int t = threadIdx.x;      // 0..63
    __shared__ u64 rem[16];
    __shared__ int kept[POST];
    __shared__ int s_nk;
    if (t < 16) rem[t] = 0ull;
    __syncthreads();

    const u64* mb = masks + (size_t)b * PRE * 16;
    const int w = t >> 2, g = t & 3;   // cross-chunk role: word w, row-group g
    int prefix = 0;

    // prefetch chunk 0
    u64 dv_cur = mb[(size_t)t * 16 + 0];
    u64 cw_cur[16];
    #pragma unroll
    for (int k = 0; k < 16; ++k)
        cw_cur[k] = mb[((size_t)(g * 16 + k)) * 16 + w];

    for (int c = 0; c < 16; ++c) {
        u64 dv_nxt = 0ull;
        u64 cw_nxt[16];
        if (c < 15) {
            const u64* nb = mb + (size_t)(c + 1) * 64 * 16;
            dv_nxt = nb[(size_t)t * 16 + (c + 1)];
            #pragma unroll
            for (int k = 0; k < 16; ++k)
                cw_nxt[k] = nb[((size_t)(g * 16 + k)) * 16 + w];
        } else {
            #pragma unroll
            for (int k = 0; k < 16; ++k) cw_nxt[k] = 0ull;
        }

        u64 alive = ~rem[c];
        int dlo = (int)(dv_cur & 0xFFFFFFFFull);
        int dhi = (int)(dv_cur >> 32);

        for (int l = 0; l < 64; ++l) {
            unsigned lo = (unsigned)__builtin_amdgcn_readlane(dlo, l);
            unsigned hi = (unsigned)__builtin_amdgcn_readlane(dhi, l);
            u64 dl = ((u64)hi << 32) | lo;
            u64 a = (alive >> l) & 1ull;
            alive &= ~(a ? dl : 0ull);
        }

        if ((alive >> t) & 1ull) {
            int pos = prefix + (int)__popcll(alive & ((1ull << t) - 1ull));
            if (pos < POST) kept[pos] = c * 64 + t;
        }
        prefix += (int)__popcll(alive);

        u64 acc = 0ull;
        #pragma unroll
        for (int k = 0; k < 16; ++k)
            if ((alive >> (g * 16 + k)) & 1ull) acc |= cw_cur[k];
        acc |= shfl_xor_u64(acc, 1);
        acc |= shfl_xor_u64(acc, 2);
        __syncthreads();
        if (g == 0 && w > c) rem[w] |= acc;
        __syncthreads();

        if (prefix >= POST) break;   // first POST kept found; rest irrelevant

        dv_cur = dv_nxt;
        #pragma unroll
        for (int k = 0; k < 16; ++k) cw_cur[k] = cw_nxt[k];
    }

    if (t == 0) s_nk = (prefix < POST) ? prefix : POST;
    __syncthreads();
    const int n = s_nk;

    float* ob = out + (size_t)b * POST * 5;
    for (int r = t; r < POST; r += 64) {
        if (r < n) {
            int i = kept[r];
            ob[r * 5 + 0] = topS[b * PRE + i];
            const float* tb = topB + ((size_t)b * PRE + i) * 4;
            ob[r * 5 + 1] = tb[0];
            ob[r * 5 + 2] = tb[1];
            ob[r * 5 + 3] = tb[2];
            ob[r * 5 + 4] = tb[3];
        } else {
            ob[r * 5 + 0] = 0.0f; ob[r * 5 + 1] = 0.0f; ob[r * 5 + 2] = 0.0f;
            ob[r * 5 + 3] = 0.0f; ob[r * 5 + 4] = 0.0f;
        }
    }
}

extern "C" void kernel_launch(void* const* d_in, const int* in_sizes, int n_in,
                              void* d_out, int out_size, void* d_ws, size_t ws_size,
                              hipStream_t stream) {
    const float* cls  = (const float*)d_in[0];
    const float* reg  = (const float*)d_in[1];
    const float* anch = (const float*)d_in[2];

    // workspace layout (~24 MB peak; no host memset — cnt zeroed in bstar):
    //   [0,       8192)     cnt   (32 counters, 256-B stride)
    //   [8192,    8448)     bstar
    //   [8448,    139520)   topS  32*1024 f32
    //   [139520,  663808)   topB  32*1024*4 f32
    //   [663808,  1712384)  cand  32*4096 u64
    //   [1712384, 6430976)  part  32*9*8192 u16 (stages 1-2)
    //                       masks 32*1024*16 u64 (stages 5-6, aliases part)
    //   [6430976, 24125696) keys  32*138240 u32 (stage 1 write, stage 3 read)
    char* ws = (char*)d_ws;
    int*      cnt   = (int*)ws;
    int*      bstar = (int*)(ws + 8192);
    float*    topS  = (float*)(ws + 8448);
    float*    topB  = (float*)(ws + 139520);
    u64*      cand  = (u64*)(ws + 663808);
    u16*      part  = (u16*)(ws + 1712384);
    u64*      masks = (u64*)(ws + 1712384);
    unsigned* keys  = (unsigned*)(ws + 6430976);

    score_kernel  <<<dim3(SBLK, B_CNT), 1024, 0, stream>>>(cls, keys, part);
    bstar_kernel  <<<B_CNT, 1024, 0, stream>>>(part, bstar, cnt);
    compact_kernel<<<dim3(SBLK, B_CNT), 1024, 0, stream>>>(keys, bstar, cnt, cand);
    lsort_kernel  <<<dim3(4, B_CNT), 512, 0, stream>>>(cnt, cand);
    merge_kernel  <<<B_CNT, 1024, 0, stream>>>(cand, reg, anch, topS, topB);
    mask_kernel   <<<dim3(16, B_CNT), 1024, 0, stream>>>(topB, masks);
    nms_kernel    <<<B_CNT, 64, 0, stream>>>(masks, topS, topB, (float*)d_out);
}